// Round 2
// baseline (486.831 us; speedup 1.0000x reference)
//
#include <hip/hip_runtime.h>
#include <math.h>

#define NN 4096
#define MM 64
#define THREADS 1024

__device__ __forceinline__ float wave_red_sum(float v) {
#pragma unroll
    for (int o = 32; o > 0; o >>= 1) v += __shfl_down(v, o, 64);
    return v;
}
__device__ __forceinline__ float wave_red_max(float v) {
#pragma unroll
    for (int o = 32; o > 0; o >>= 1) v = fmaxf(v, __shfl_down(v, o, 64));
    return v;
}

// Block-wide reductions over 1024 threads (16 waves). scratch needs >= 17 floats.
__device__ __forceinline__ float block_sum(float v, float* scratch) {
    const int tid = threadIdx.x;
    const int lane = tid & 63, wid = tid >> 6;
    v = wave_red_sum(v);
    if (lane == 0) scratch[wid] = v;
    __syncthreads();
    if (tid < 64) {
        float x = (tid < 16) ? scratch[tid] : 0.0f;
        x = wave_red_sum(x);
        if (tid == 0) scratch[16] = x;
    }
    __syncthreads();
    float r = scratch[16];
    __syncthreads();
    return r;
}
__device__ __forceinline__ float block_max(float v, float* scratch) {
    const int tid = threadIdx.x;
    const int lane = tid & 63, wid = tid >> 6;
    v = wave_red_max(v);
    if (lane == 0) scratch[wid] = v;
    __syncthreads();
    if (tid < 64) {
        float x = (tid < 16) ? scratch[tid] : -INFINITY;
        x = wave_red_max(x);
        if (tid == 0) scratch[16] = x;
    }
    __syncthreads();
    float r = scratch[16];
    __syncthreads();
    return r;
}

extern "C" __global__ void __launch_bounds__(THREADS)
ntm_head_kernel(const float* __restrict__ memory, const float* __restrict__ k,
                const float* __restrict__ beta, const float* __restrict__ prev_w,
                const float* __restrict__ g, const float* __restrict__ s,
                const float* __restrict__ gamma, float* __restrict__ out) {
    __shared__ __align__(16) float kk[MM];
    __shared__ float wg[NN];     // 16 KB
    __shared__ float scratch[32];
    __shared__ float knorm_sh;

    const int b = blockIdx.x;
    const int tid = threadIdx.x;
    const float* __restrict__ memB = memory + (size_t)b * NN * MM;

    // Early independent loads: prev_w (coalesced) and per-batch scalars.
    float pw[4];
#pragma unroll
    for (int j = 0; j < 4; ++j)
        pw[j] = prev_w[(size_t)b * NN + tid + j * THREADS];
    const float beta_b = beta[b];
    const float g_b = g[b];
    const float s0 = s[b * 3], s1 = s[b * 3 + 1], s2 = s[b * 3 + 2];
    const float gamma_b = gamma[b];

    // k into LDS + k_norm (wave 0; no extra sync needed — wave0 reduces its own regs)
    if (tid < 64) {
        const float kv = k[b * MM + tid];
        kk[tid] = kv;
        const float sk = wave_red_sum(kv * kv);
        if (tid == 0) knorm_sh = fmaxf(sqrtf(sk), 1e-8f);
    }
    __syncthreads();

    // ---- Phase A: per-thread row ownership, reduction-free ----
    // Thread owns rows n = tid + j*1024, j=0..3. k broadcast from LDS.
    float d[4] = {0.f, 0.f, 0.f, 0.f};
    float q[4] = {0.f, 0.f, 0.f, 0.f};
    const float* base = memB + (size_t)tid * MM;
#pragma unroll
    for (int i = 0; i < 16; ++i) {
        const float4 kf = *(const float4*)(kk + i * 4);   // LDS broadcast, conflict-free
#pragma unroll
        for (int j = 0; j < 4; ++j) {
            const float4 mv = *(const float4*)(base + (size_t)j * THREADS * MM + i * 4);
            d[j] += mv.x * kf.x + mv.y * kf.y + mv.z * kf.z + mv.w * kf.w;
            q[j] += mv.x * mv.x + mv.y * mv.y + mv.z * mv.z + mv.w * mv.w;
        }
    }

    const float knorm = knorm_sh;

    // ---- Phase B: scaled similarity + block max ----
    float val[4];
    float lmax = -INFINITY;
#pragma unroll
    for (int j = 0; j < 4; ++j) {
        const float mn = fmaxf(sqrtf(q[j]), 1e-8f);
        const float v = beta_b * (d[j] / (knorm * mn));
        val[j] = v;
        lmax = fmaxf(lmax, v);
    }
    const float mx = block_max(lmax, scratch);

    // ---- Phase C: softmax ----
    float e[4];
    float lsum = 0.0f;
#pragma unroll
    for (int j = 0; j < 4; ++j) {
        e[j] = expf(val[j] - mx);
        lsum += e[j];
    }
    const float sumE = block_sum(lsum, scratch);

    // ---- Phase D: gated interpolation into LDS ----
#pragma unroll
    for (int j = 0; j < 4; ++j) {
        const int n = tid + j * THREADS;
        const float wc = e[j] / sumE;
        wg[n] = g_b * wc + (1.0f - g_b) * pw[j];
    }
    __syncthreads();

    // ---- Phase E: circular 3-tap shift, sharpen, normalize ----
    float wp[4];
    float lsum2 = 0.0f;
#pragma unroll
    for (int j = 0; j < 4; ++j) {
        const int n = tid + j * THREADS;
        const int nm = (n + NN - 1) & (NN - 1);
        const int np_ = (n + 1) & (NN - 1);
        const float ws = s0 * wg[nm] + s1 * wg[n] + s2 * wg[np_];
        const float p = (float)pow((double)ws, (double)gamma_b);
        wp[j] = p;
        lsum2 += p;
    }
    const float sumP = block_sum(lsum2, scratch);
    const float denom = sumP + 1e-16f;
#pragma unroll
    for (int j = 0; j < 4; ++j) {
        const int n = tid + j * THREADS;
        out[(size_t)b * NN + n] = wp[j] / denom;
    }
}

extern "C" void kernel_launch(void* const* d_in, const int* in_sizes, int n_in,
                              void* d_out, int out_size, void* d_ws, size_t ws_size,
                              hipStream_t stream) {
    const float* memory = (const float*)d_in[0];
    const float* k      = (const float*)d_in[1];
    const float* beta   = (const float*)d_in[2];
    const float* prev_w = (const float*)d_in[3];
    const float* g      = (const float*)d_in[4];
    const float* s      = (const float*)d_in[5];
    const float* gamma  = (const float*)d_in[6];
    float* out = (float*)d_out;

    const int B = in_sizes[2];  // beta is [B,1]
    ntm_head_kernel<<<B, THREADS, 0, stream>>>(memory, k, beta, prev_w, g, s, gamma, out);
}

// Round 3
// 378.968 us; speedup vs baseline: 1.2846x; 1.2846x over previous
//
#include <hip/hip_runtime.h>
#include <math.h>

#define NN 4096
#define MM 64
#define THREADS 1024

// DPP row_shr accumulate: lane i += lane (i-N) within its 16-lane row.
// After N=1,2,4,8, lane 15 of each row holds the full 16-lane sum.
template <int CTRL>
__device__ __forceinline__ float dpp_add(float v) {
    int r = __builtin_amdgcn_update_dpp(0, __float_as_int(v), CTRL, 0xf, 0xf, true);
    return v + __int_as_float(r);
}

__device__ __forceinline__ float wave_red_sum(float v) {
#pragma unroll
    for (int o = 32; o > 0; o >>= 1) v += __shfl_down(v, o, 64);
    return v;
}
__device__ __forceinline__ float wave_red_max(float v) {
#pragma unroll
    for (int o = 32; o > 0; o >>= 1) v = fmaxf(v, __shfl_down(v, o, 64));
    return v;
}

// Block-wide reductions over 1024 threads (16 waves). scratch needs >= 17 floats.
__device__ __forceinline__ float block_sum(float v, float* scratch) {
    const int tid = threadIdx.x;
    const int lane = tid & 63, wid = tid >> 6;
    v = wave_red_sum(v);
    if (lane == 0) scratch[wid] = v;
    __syncthreads();
    if (tid < 64) {
        float x = (tid < 16) ? scratch[tid] : 0.0f;
        x = wave_red_sum(x);
        if (tid == 0) scratch[16] = x;
    }
    __syncthreads();
    float r = scratch[16];
    __syncthreads();
    return r;
}
__device__ __forceinline__ float block_max(float v, float* scratch) {
    const int tid = threadIdx.x;
    const int lane = tid & 63, wid = tid >> 6;
    v = wave_red_max(v);
    if (lane == 0) scratch[wid] = v;
    __syncthreads();
    if (tid < 64) {
        float x = (tid < 16) ? scratch[tid] : -INFINITY;
        x = wave_red_max(x);
        if (tid == 0) scratch[16] = x;
    }
    __syncthreads();
    float r = scratch[16];
    __syncthreads();
    return r;
}

extern "C" __global__ void __launch_bounds__(THREADS)
ntm_head_kernel(const float* __restrict__ memory, const float* __restrict__ k,
                const float* __restrict__ beta, const float* __restrict__ prev_w,
                const float* __restrict__ g, const float* __restrict__ s,
                const float* __restrict__ gamma, float* __restrict__ out) {
    __shared__ float dotA[NN];   // 16 KB
    __shared__ float sqA[NN];    // 16 KB
    __shared__ float wg[NN];     // 16 KB
    __shared__ __align__(16) float kk[MM];
    __shared__ float scratch[32];
    __shared__ float knorm_sh;

    const int b = blockIdx.x;
    const int tid = threadIdx.x;
    const float* __restrict__ memB = memory + (size_t)b * NN * MM;

    // Early independent loads: prev_w (coalesced) and per-batch scalars.
    float pw[4];
#pragma unroll
    for (int j = 0; j < 4; ++j)
        pw[j] = prev_w[(size_t)b * NN + tid + j * THREADS];
    const float beta_b = beta[b];
    const float g_b = g[b];
    const float s0 = s[b * 3], s1 = s[b * 3 + 1], s2 = s[b * 3 + 2];
    const float gamma_b = gamma[b];

    // k into LDS + k_norm (wave 0 reduces its own registers)
    if (tid < 64) {
        const float kv = k[b * MM + tid];
        kk[tid] = kv;
        const float sk = wave_red_sum(kv * kv);
        if (tid == 0) knorm_sh = fmaxf(sqrtf(sk), 1e-8f);
    }
    __syncthreads();

    // per-lane slice of k: 16-lane segment covers one row (64 floats, 4/lane)
    const int m4 = (tid & 15) * 4;
    const float kx = kk[m4], ky = kk[m4 + 1], kz = kk[m4 + 2], kw = kk[m4 + 3];

    // ---- Phase A: fully-coalesced stream; 16-lane DPP segment reduction ----
    // Wave reads contiguous 1 KB per instruction; each 16-lane segment = 1 row.
#pragma unroll 4
    for (int it = 0; it < 64; ++it) {
        const float4 mv = *(const float4*)(memB + (size_t)it * 4096 + tid * 4);
        float d = mv.x * kx + mv.y * ky + mv.z * kz + mv.w * kw;
        float q = mv.x * mv.x + mv.y * mv.y + mv.z * mv.z + mv.w * mv.w;
        d = dpp_add<0x111>(d);  // row_shr:1
        d = dpp_add<0x112>(d);  // row_shr:2
        d = dpp_add<0x114>(d);  // row_shr:4
        d = dpp_add<0x118>(d);  // row_shr:8
        q = dpp_add<0x111>(q);
        q = dpp_add<0x112>(q);
        q = dpp_add<0x114>(q);
        q = dpp_add<0x118>(q);
        if ((tid & 15) == 15) {
            const int n = it * 64 + (tid >> 4);
            dotA[n] = d;
            sqA[n] = q;
        }
    }
    __syncthreads();

    const float knorm = knorm_sh;

    // ---- Phase B: scaled similarity + block max ----
    float val[4];
    float lmax = -INFINITY;
#pragma unroll
    for (int j = 0; j < 4; ++j) {
        const int n = tid + j * THREADS;
        const float mn = fmaxf(sqrtf(sqA[n]), 1e-8f);
        const float v = beta_b * (dotA[n] / (knorm * mn));
        val[j] = v;
        lmax = fmaxf(lmax, v);
    }
    const float mx = block_max(lmax, scratch);

    // ---- Phase C: softmax ----
    float e[4];
    float lsum = 0.0f;
#pragma unroll
    for (int j = 0; j < 4; ++j) {
        e[j] = expf(val[j] - mx);
        lsum += e[j];
    }
    const float sumE = block_sum(lsum, scratch);

    // ---- Phase D: gated interpolation into LDS ----
#pragma unroll
    for (int j = 0; j < 4; ++j) {
        const int n = tid + j * THREADS;
        const float wc = e[j] / sumE;
        wg[n] = g_b * wc + (1.0f - g_b) * pw[j];
    }
    __syncthreads();

    // ---- Phase E: circular 3-tap shift, sharpen, normalize ----
    float wp[4];
    float lsum2 = 0.0f;
#pragma unroll
    for (int j = 0; j < 4; ++j) {
        const int n = tid + j * THREADS;
        const int nm = (n + NN - 1) & (NN - 1);
        const int np_ = (n + 1) & (NN - 1);
        const float ws = s0 * wg[nm] + s1 * wg[n] + s2 * wg[np_];
        const float p = (float)pow((double)ws, (double)gamma_b);
        wp[j] = p;
        lsum2 += p;
    }
    const float sumP = block_sum(lsum2, scratch);
    const float denom = sumP + 1e-16f;
#pragma unroll
    for (int j = 0; j < 4; ++j) {
        const int n = tid + j * THREADS;
        out[(size_t)b * NN + n] = wp[j] / denom;
    }
}

extern "C" void kernel_launch(void* const* d_in, const int* in_sizes, int n_in,
                              void* d_out, int out_size, void* d_ws, size_t ws_size,
                              hipStream_t stream) {
    const float* memory = (const float*)d_in[0];
    const float* k      = (const float*)d_in[1];
    const float* beta   = (const float*)d_in[2];
    const float* prev_w = (const float*)d_in[3];
    const float* g      = (const float*)d_in[4];
    const float* s      = (const float*)d_in[5];
    const float* gamma  = (const float*)d_in[6];
    float* out = (float*)d_out;

    const int B = in_sizes[2];  // beta is [B,1]
    ntm_head_kernel<<<B, THREADS, 0, stream>>>(memory, k, beta, prev_w, g, s, gamma, out);
}